// Round 6
// baseline (268.120 us; speedup 1.0000x reference)
//
#include <hip/hip_runtime.h>
#include <stdint.h>

// Problem constants (from reference)
#define NB   8
#define AB   256
#define HB   128
#define WB   128
#define CB   19
#define CP1  20
#define PLANE (HB*WB)          // 16384
#define NPIX  (NB*PLANE)       // 131072

typedef __attribute__((ext_vector_type(8))) short bf8_t;
typedef __attribute__((ext_vector_type(4))) float f4_t;
union ABu { bf8_t v; unsigned short u[8]; };

__device__ inline unsigned short f2bf(float f) {      // RNE fp32->bf16 (finite inputs)
    unsigned int u = __float_as_uint(f);
    return (unsigned short)((u + 0x7FFFu + ((u >> 16) & 1u)) >> 16);
}

// ---------------------------------------------------------------------------
// Kernel A: nearest-neighbor label downsample -> raw u8 + mapped u8, + counts
// ---------------------------------------------------------------------------
__global__ __launch_bounds__(256) void k_labels(const int* __restrict__ target,
                                                unsigned char* __restrict__ labels,
                                                unsigned char* __restrict__ lab0,
                                                float* __restrict__ counts) {
    __shared__ int hist[CP1];
    int tid = threadIdx.x;
    if (tid < CP1) hist[tid] = 0;
    __syncthreads();

    int p = blockIdx.x * 256 + tid;          // p in [0, NPIX)
    int n   = p >> 14;
    int rem = p & 16383;
    int h   = rem >> 7;
    int w   = rem & 127;
    size_t idx = (size_t)n * 1048576 + (size_t)h * 8192 + (size_t)w * 8;
    int l = target[idx];
    labels[p] = (unsigned char)l;
    int m = (l == 255) ? 0 : ((l >= 0 && l < CP1) ? l : 0);
    lab0[p] = (unsigned char)m;
    atomicAdd(&hist[m], 1);
    __syncthreads();
    if (tid < CP1) atomicAdd(&counts[tid], (float)hist[tid]);
}

// ---------------------------------------------------------------------------
// Kernel B (v4): per-class sum/sumsq via MFMA, atomic-free epilogue.
// S[l,a] = onehot[l,p] . F[a,p]; one-hot built in-register from labels.
// Block = 4 waves; wave owns 16 channels, block owns 64 ch x 1024 px.
// Grid = 8n x 16pc x 4cg = 512. Per-block partials P[bx][40][64] (no atomics).
// ---------------------------------------------------------------------------
__global__ __launch_bounds__(256) void k_stats(const float* __restrict__ features,
                                               const unsigned char* __restrict__ lab0,
                                               float* __restrict__ gpart) {
    __shared__ uint2 labs[128];              // 1024 labels
    const int tid  = threadIdx.x;
    const int lane = tid & 63;
    const int w    = tid >> 6;

    const int bx = blockIdx.x;               // [0, 512)
    const int cg = bx & 3;                   // channel group (64 ch)
    const int pc = (bx >> 2) & 15;           // pixel chunk (1024 px)
    const int n  = bx >> 6;

    if (tid < 128)
        labs[tid] = ((const uint2*)(lab0 + (size_t)n * PLANE + pc * 1024))[tid];
    __syncthreads();

    const int col = lane & 15;               // channel-within-tile (B col, D col)
    const int pg  = (lane >> 4) * 8;         // k sub-offset within 32-pixel step
    const int ch  = cg * 64 + w * 16 + col;
    const float* fbase = features + ((size_t)(n * AB + ch)) * PLANE + pc * 1024 + pg;

    f4_t aS0 = {0.f,0.f,0.f,0.f}, aQ0 = {0.f,0.f,0.f,0.f};   // classes 0-15
    f4_t aS1 = {0.f,0.f,0.f,0.f}, aQ1 = {0.f,0.f,0.f,0.f};   // classes 16-19

    const unsigned int t0 = (unsigned int)col;
    const unsigned int t1 = 16u + (unsigned int)col;

    #pragma unroll 4
    for (int t = 0; t < 32; ++t) {
        float4 va = *(const float4*)(fbase + t * 32);
        float4 vb = *(const float4*)(fbase + t * 32 + 4);
        uint2 lw = labs[(t * 32 + pg) >> 3];
        unsigned int bb[8] = { lw.x & 255u, (lw.x >> 8) & 255u, (lw.x >> 16) & 255u, lw.x >> 24,
                               lw.y & 255u, (lw.y >> 8) & 255u, (lw.y >> 16) & 255u, lw.y >> 24 };
        float fv[8] = { va.x, va.y, va.z, va.w, vb.x, vb.y, vb.z, vb.w };
        ABu a0, a1, bs, bq;
        #pragma unroll
        for (int j = 0; j < 8; ++j) {
            a0.u[j] = (bb[j] == t0) ? (unsigned short)0x3F80 : (unsigned short)0;
            a1.u[j] = (bb[j] == t1) ? (unsigned short)0x3F80 : (unsigned short)0;
            bs.u[j] = f2bf(fv[j]);
            bq.u[j] = f2bf(fv[j] * fv[j]);
        }
        aS0 = __builtin_amdgcn_mfma_f32_16x16x32_bf16(a0.v, bs.v, aS0, 0, 0, 0);
        aS1 = __builtin_amdgcn_mfma_f32_16x16x32_bf16(a1.v, bs.v, aS1, 0, 0, 0);
        aQ0 = __builtin_amdgcn_mfma_f32_16x16x32_bf16(a0.v, bq.v, aQ0, 0, 0, 0);
        aQ1 = __builtin_amdgcn_mfma_f32_16x16x32_bf16(a1.v, bq.v, aQ1, 0, 0, 0);
    }

    // D layout (m89): col = lane&15 (channel), row = (lane>>4)*4 + reg (class).
    // Non-atomic per-block partials: P[bx][row 0-19 sum | 20-39 sq][64 ch].
    float* P = gpart + (size_t)bx * (40 * 64);
    const int chl = w * 16 + col;
    const int rbase = (lane >> 4) * 4;
    #pragma unroll
    for (int r = 0; r < 4; ++r) {
        P[(rbase + r) * 64 + chl]      = aS0[r];
        P[(20 + rbase + r) * 64 + chl] = aQ0[r];
    }
    if (rbase == 0) {                        // rows 0-3 of tile2 = classes 16-19
        #pragma unroll
        for (int r = 0; r < 4; ++r) {
            P[(16 + r) * 64 + chl] = aS1[r];
            P[(36 + r) * 64 + chl] = aQ1[r];
        }
    }
}

// ---------------------------------------------------------------------------
// Kernel C: reduce partials, ave/var/new_cov -> sigma2 table [CP1][CB]
// ---------------------------------------------------------------------------
__global__ __launch_bounds__(256) void k_table(const float* __restrict__ counts,
                                               const float* __restrict__ gpart,
                                               const float* __restrict__ fcw,
                                               const float* __restrict__ Ave,
                                               const float* __restrict__ CoV,
                                               const float* __restrict__ Amount,
                                               const int* __restrict__ ratio_p,
                                               float* __restrict__ table) {
    __shared__ float ncov_s[256];
    __shared__ float wl_s[256];
    int t = threadIdx.x;
    int l = blockIdx.x;

    // channel t lives in channel-group cg = t>>6; its blocks are bx = cg + 4*npc
    int cg  = t >> 6;
    int chl = t & 63;
    float sum = 0.f, sq = 0.f;
    #pragma unroll 4
    for (int npc = 0; npc < 128; ++npc) {    // n*16 + pc
        const float* P = gpart + (size_t)(cg + 4 * npc) * (40 * 64);
        sum += P[l * 64 + chl];
        sq  += P[(20 + l) * 64 + chl];
    }

    float cnt  = counts[l];
    float cntc = (cnt == 0.f) ? 1.f : cnt;
    float ave  = sum / cntc;
    float var  = sq / cntc - ave * ave;
    float denom = cnt + Amount[l];
    float wcv  = (denom > 0.f) ? cnt / denom : 0.f;
    float d0   = Ave[l * 256 + t] - ave;
    float ncov = CoV[l * 256 + t] * (1.f - wcv) + var * wcv + wcv * (1.f - wcv) * d0 * d0;

    ncov_s[t] = ncov;
    int lwr = (l < CB) ? l : (CB - 1);       // row 19 never used (counts[19]==0)
    wl_s[t] = fcw[lwr * 256 + t];
    __syncthreads();

    int wv = t >> 6, lane = t & 63;
    float ratio_f = (float)(*ratio_p);
    for (int c = wv; c < CB; c += 4) {
        float4 nc = *(const float4*)&ncov_s[lane * 4];
        float4 wl = *(const float4*)&wl_s[lane * 4];
        float4 wc = *(const float4*)&fcw[c * 256 + lane * 4];
        float e0 = wc.x - wl.x, e1 = wc.y - wl.y, e2 = wc.z - wl.z, e3 = wc.w - wl.w;
        float r = nc.x * e0 * e0 + nc.y * e1 * e1 + nc.z * e2 * e2 + nc.w * e3 * e3;
        #pragma unroll
        for (int off = 32; off; off >>= 1) r += __shfl_down(r, off);
        if (lane == 0) table[l * CB + c] = ratio_f * r;
    }
}

// ---------------------------------------------------------------------------
// Kernel D: out[n,c,h,w] = y[n,c,h,w] + 0.5 * table[lab[n,h,w]][c] * keep
// ---------------------------------------------------------------------------
__global__ __launch_bounds__(256) void k_apply(const float* __restrict__ y,
                                               const unsigned char* __restrict__ labels,
                                               const float* __restrict__ table,
                                               float* __restrict__ out) {
    __shared__ float tab[CP1 * CB];
    int tid = threadIdx.x;
    for (int i = tid; i < CP1 * CB; i += 256) tab[i] = table[i];
    __syncthreads();

    int b = blockIdx.x;
    int chunk = b & 3;
    int c = (b >> 2) % CB;
    int n = b / (4 * CB);

    const float* ybase = y + ((size_t)(n * CB + c)) * PLANE;
    float* obase = out + ((size_t)(n * CB + c)) * PLANE;
    const unsigned char* lbase = labels + (size_t)n * PLANE;

    #pragma unroll
    for (int it = 0; it < 4; ++it) {
        int pix = chunk * 4096 + it * 1024 + tid * 4;
        float4 yv = *reinterpret_cast<const float4*>(ybase + pix);
        unsigned int lwv = *reinterpret_cast<const unsigned int*>(lbase + pix);
        float ya[4] = {yv.x, yv.y, yv.z, yv.w};
        float o[4];
        #pragma unroll
        for (int j = 0; j < 4; ++j) {
            int l = (lwv >> (8 * j)) & 255;
            bool keep = (l != 255);
            int lab0i = keep ? (l < CP1 ? l : 0) : 0;
            float s = tab[lab0i * CB + c];
            o[j] = ya[j] + (keep ? 0.5f * s : 0.f);
        }
        *reinterpret_cast<float4*>(obase + pix) = make_float4(o[0], o[1], o[2], o[3]);
    }
}

// ---------------------------------------------------------------------------
extern "C" void kernel_launch(void* const* d_in, const int* in_sizes, int n_in,
                              void* d_out, int out_size, void* d_ws, size_t ws_size,
                              hipStream_t stream) {
    const float* features = (const float*)d_in[0];   // [8,256,128,128]
    const float* y        = (const float*)d_in[1];   // [8,19,128,128]
    const float* fcw      = (const float*)d_in[2];   // [19,256]
    const float* Ave      = (const float*)d_in[3];   // [20,256]
    const float* CoV      = (const float*)d_in[4];   // [20,256]
    const float* Amount   = (const float*)d_in[5];   // [20]
    const int*   target   = (const int*)d_in[6];     // [8,1024,1024]
    const int*   ratio    = (const int*)d_in[7];     // scalar

    char* ws = (char*)d_ws;
    float* counts = (float*)(ws + 0);                       // 20 f32 (pad 128 B)
    float* gpart  = (float*)(ws + 128);                     // 512*40*64 f32 = 5242880 B
    unsigned char* labels = (unsigned char*)(ws + 5243008); // 131072 u8 (raw)
    unsigned char* lab0   = (unsigned char*)(ws + 5374080); // 131072 u8 (mapped)
    float* table  = (float*)(ws + 5505152);                 // 20*19 f32
    float* out    = (float*)d_out;

    // zero only counts (partials are fully overwritten each launch)
    hipMemsetAsync(counts, 0, 128, stream);

    k_labels<<<NPIX / 256,  256, 0, stream>>>(target, labels, lab0, counts);
    k_stats <<<NB * 16 * 4, 256, 0, stream>>>(features, lab0, gpart);
    k_table <<<CP1,         256, 0, stream>>>(counts, gpart, fcw, Ave, CoV, Amount, ratio, table);
    k_apply <<<NB * CB * 4, 256, 0, stream>>>(y, labels, table, out);
}

// Round 7
// 263.823 us; speedup vs baseline: 1.0163x; 1.0163x over previous
//
#include <hip/hip_runtime.h>
#include <stdint.h>

// Problem constants (from reference)
#define NB   8
#define AB   256
#define HB   128
#define WB   128
#define CB   19
#define CP1  20
#define PLANE (HB*WB)          // 16384
#define NPIX  (NB*PLANE)       // 131072
#define NBLK  1024             // k_stats grid: 8n x 32pc x 4cg

typedef __attribute__((ext_vector_type(8))) short bf8_t;
typedef __attribute__((ext_vector_type(4))) float f4_t;
union ABu { bf8_t v; unsigned short u[8]; };

__device__ inline unsigned short f2bf(float f) {      // RNE fp32->bf16 (finite inputs)
    unsigned int u = __float_as_uint(f);
    return (unsigned short)((u + 0x7FFFu + ((u >> 16) & 1u)) >> 16);
}

// ---------------------------------------------------------------------------
// Kernel A: nearest-neighbor label downsample -> raw u8 + mapped u8, + counts
// ---------------------------------------------------------------------------
__global__ __launch_bounds__(256) void k_labels(const int* __restrict__ target,
                                                unsigned char* __restrict__ labels,
                                                unsigned char* __restrict__ lab0,
                                                float* __restrict__ counts) {
    __shared__ int hist[CP1];
    int tid = threadIdx.x;
    if (tid < CP1) hist[tid] = 0;
    __syncthreads();

    int p = blockIdx.x * 256 + tid;          // p in [0, NPIX)
    int n   = p >> 14;
    int rem = p & 16383;
    int h   = rem >> 7;
    int w   = rem & 127;
    size_t idx = (size_t)n * 1048576 + (size_t)h * 8192 + (size_t)w * 8;
    int l = target[idx];
    labels[p] = (unsigned char)l;
    int m = (l == 255) ? 0 : ((l >= 0 && l < CP1) ? l : 0);
    lab0[p] = (unsigned char)m;
    atomicAdd(&hist[m], 1);
    __syncthreads();
    if (tid < CP1) atomicAdd(&counts[tid], (float)hist[tid]);
}

// ---------------------------------------------------------------------------
// Kernel B (v5): per-class sum/sumsq via MFMA, atomic-free epilogue.
// S[l,a] = onehot[l,p] . F[a,p]; one-hot built in-register from labels.
// Block = 4 waves; wave owns 16 channels, block owns 64 ch x 512 px.
// Grid = 8n x 32pc x 4cg = 1024 (4 blocks/CU, 4 waves/SIMD — latency hiding).
// Per-block partials P[bx][40][64] (no atomics). unroll 8 for deep MLP.
// ---------------------------------------------------------------------------
__global__ __launch_bounds__(256) void k_stats(const float* __restrict__ features,
                                               const unsigned char* __restrict__ lab0,
                                               float* __restrict__ gpart) {
    __shared__ uint2 labs[64];               // 512 labels
    const int tid  = threadIdx.x;
    const int lane = tid & 63;
    const int w    = tid >> 6;

    const int bx = blockIdx.x;               // [0, 1024)
    const int cg = bx & 3;                   // channel group (64 ch)
    const int pc = (bx >> 2) & 31;           // pixel chunk (512 px)
    const int n  = bx >> 7;

    if (tid < 64)
        labs[tid] = ((const uint2*)(lab0 + (size_t)n * PLANE + pc * 512))[tid];
    __syncthreads();

    const int col = lane & 15;               // channel-within-tile (B col, D col)
    const int pg  = (lane >> 4) * 8;         // k sub-offset within 32-pixel step
    const int ch  = cg * 64 + w * 16 + col;
    const float* fbase = features + ((size_t)(n * AB + ch)) * PLANE + pc * 512 + pg;

    f4_t aS0 = {0.f,0.f,0.f,0.f}, aQ0 = {0.f,0.f,0.f,0.f};   // classes 0-15
    f4_t aS1 = {0.f,0.f,0.f,0.f}, aQ1 = {0.f,0.f,0.f,0.f};   // classes 16-19

    const unsigned int t0 = (unsigned int)col;
    const unsigned int t1 = 16u + (unsigned int)col;

    #pragma unroll 8
    for (int t = 0; t < 16; ++t) {
        float4 va = *(const float4*)(fbase + t * 32);
        float4 vb = *(const float4*)(fbase + t * 32 + 4);
        uint2 lw = labs[(t * 32 + pg) >> 3];
        unsigned int bb[8] = { lw.x & 255u, (lw.x >> 8) & 255u, (lw.x >> 16) & 255u, lw.x >> 24,
                               lw.y & 255u, (lw.y >> 8) & 255u, (lw.y >> 16) & 255u, lw.y >> 24 };
        float fv[8] = { va.x, va.y, va.z, va.w, vb.x, vb.y, vb.z, vb.w };
        ABu a0, a1, bs, bq;
        #pragma unroll
        for (int j = 0; j < 8; ++j) {
            a0.u[j] = (bb[j] == t0) ? (unsigned short)0x3F80 : (unsigned short)0;
            a1.u[j] = (bb[j] == t1) ? (unsigned short)0x3F80 : (unsigned short)0;
            bs.u[j] = f2bf(fv[j]);
            bq.u[j] = f2bf(fv[j] * fv[j]);
        }
        aS0 = __builtin_amdgcn_mfma_f32_16x16x32_bf16(a0.v, bs.v, aS0, 0, 0, 0);
        aS1 = __builtin_amdgcn_mfma_f32_16x16x32_bf16(a1.v, bs.v, aS1, 0, 0, 0);
        aQ0 = __builtin_amdgcn_mfma_f32_16x16x32_bf16(a0.v, bq.v, aQ0, 0, 0, 0);
        aQ1 = __builtin_amdgcn_mfma_f32_16x16x32_bf16(a1.v, bq.v, aQ1, 0, 0, 0);
    }

    // D layout (m89): col = lane&15 (channel), row = (lane>>4)*4 + reg (class).
    // Non-atomic per-block partials: P[bx][row 0-19 sum | 20-39 sq][64 ch].
    float* P = gpart + (size_t)bx * (40 * 64);
    const int chl = w * 16 + col;
    const int rbase = (lane >> 4) * 4;
    #pragma unroll
    for (int r = 0; r < 4; ++r) {
        P[(rbase + r) * 64 + chl]      = aS0[r];
        P[(20 + rbase + r) * 64 + chl] = aQ0[r];
    }
    if (rbase == 0) {                        // rows 0-3 of tile2 = classes 16-19
        #pragma unroll
        for (int r = 0; r < 4; ++r) {
            P[(16 + r) * 64 + chl] = aS1[r];
            P[(36 + r) * 64 + chl] = aQ1[r];
        }
    }
}

// ---------------------------------------------------------------------------
// Kernel C: reduce partials, ave/var/new_cov -> sigma2 table [CP1][CB]
// ---------------------------------------------------------------------------
__global__ __launch_bounds__(256) void k_table(const float* __restrict__ counts,
                                               const float* __restrict__ gpart,
                                               const float* __restrict__ fcw,
                                               const float* __restrict__ Ave,
                                               const float* __restrict__ CoV,
                                               const float* __restrict__ Amount,
                                               const int* __restrict__ ratio_p,
                                               float* __restrict__ table) {
    __shared__ float ncov_s[256];
    __shared__ float wl_s[256];
    int t = threadIdx.x;
    int l = blockIdx.x;

    // channel t lives in channel-group cg = t>>6; its blocks are bx = cg + 4*npc
    int cg  = t >> 6;
    int chl = t & 63;
    float sum = 0.f, sq = 0.f;
    #pragma unroll 8
    for (int npc = 0; npc < 256; ++npc) {    // n*32 + pc
        const float* P = gpart + (size_t)(cg + 4 * npc) * (40 * 64);
        sum += P[l * 64 + chl];
        sq  += P[(20 + l) * 64 + chl];
    }

    float cnt  = counts[l];
    float cntc = (cnt == 0.f) ? 1.f : cnt;
    float ave  = sum / cntc;
    float var  = sq / cntc - ave * ave;
    float denom = cnt + Amount[l];
    float wcv  = (denom > 0.f) ? cnt / denom : 0.f;
    float d0   = Ave[l * 256 + t] - ave;
    float ncov = CoV[l * 256 + t] * (1.f - wcv) + var * wcv + wcv * (1.f - wcv) * d0 * d0;

    ncov_s[t] = ncov;
    int lwr = (l < CB) ? l : (CB - 1);       // row 19 never used (counts[19]==0)
    wl_s[t] = fcw[lwr * 256 + t];
    __syncthreads();

    int wv = t >> 6, lane = t & 63;
    float ratio_f = (float)(*ratio_p);
    for (int c = wv; c < CB; c += 4) {
        float4 nc = *(const float4*)&ncov_s[lane * 4];
        float4 wl = *(const float4*)&wl_s[lane * 4];
        float4 wc = *(const float4*)&fcw[c * 256 + lane * 4];
        float e0 = wc.x - wl.x, e1 = wc.y - wl.y, e2 = wc.z - wl.z, e3 = wc.w - wl.w;
        float r = nc.x * e0 * e0 + nc.y * e1 * e1 + nc.z * e2 * e2 + nc.w * e3 * e3;
        #pragma unroll
        for (int off = 32; off; off >>= 1) r += __shfl_down(r, off);
        if (lane == 0) table[l * CB + c] = ratio_f * r;
    }
}

// ---------------------------------------------------------------------------
// Kernel D: out[n,c,h,w] = y[n,c,h,w] + 0.5 * table[lab[n,h,w]][c] * keep
// ---------------------------------------------------------------------------
__global__ __launch_bounds__(256) void k_apply(const float* __restrict__ y,
                                               const unsigned char* __restrict__ labels,
                                               const float* __restrict__ table,
                                               float* __restrict__ out) {
    __shared__ float tab[CP1 * CB];
    int tid = threadIdx.x;
    for (int i = tid; i < CP1 * CB; i += 256) tab[i] = table[i];
    __syncthreads();

    int b = blockIdx.x;
    int chunk = b & 3;
    int c = (b >> 2) % CB;
    int n = b / (4 * CB);

    const float* ybase = y + ((size_t)(n * CB + c)) * PLANE;
    float* obase = out + ((size_t)(n * CB + c)) * PLANE;
    const unsigned char* lbase = labels + (size_t)n * PLANE;

    #pragma unroll
    for (int it = 0; it < 4; ++it) {
        int pix = chunk * 4096 + it * 1024 + tid * 4;
        float4 yv = *reinterpret_cast<const float4*>(ybase + pix);
        unsigned int lwv = *reinterpret_cast<const unsigned int*>(lbase + pix);
        float ya[4] = {yv.x, yv.y, yv.z, yv.w};
        float o[4];
        #pragma unroll
        for (int j = 0; j < 4; ++j) {
            int l = (lwv >> (8 * j)) & 255;
            bool keep = (l != 255);
            int lab0i = keep ? (l < CP1 ? l : 0) : 0;
            float s = tab[lab0i * CB + c];
            o[j] = ya[j] + (keep ? 0.5f * s : 0.f);
        }
        *reinterpret_cast<float4*>(obase + pix) = make_float4(o[0], o[1], o[2], o[3]);
    }
}

// ---------------------------------------------------------------------------
extern "C" void kernel_launch(void* const* d_in, const int* in_sizes, int n_in,
                              void* d_out, int out_size, void* d_ws, size_t ws_size,
                              hipStream_t stream) {
    const float* features = (const float*)d_in[0];   // [8,256,128,128]
    const float* y        = (const float*)d_in[1];   // [8,19,128,128]
    const float* fcw      = (const float*)d_in[2];   // [19,256]
    const float* Ave      = (const float*)d_in[3];   // [20,256]
    const float* CoV      = (const float*)d_in[4];   // [20,256]
    const float* Amount   = (const float*)d_in[5];   // [20]
    const int*   target   = (const int*)d_in[6];     // [8,1024,1024]
    const int*   ratio    = (const int*)d_in[7];     // scalar

    char* ws = (char*)d_ws;
    float* counts = (float*)(ws + 0);                        // 20 f32 (pad 128 B)
    float* gpart  = (float*)(ws + 128);                      // 1024*40*64 f32 = 10485760 B
    unsigned char* labels = (unsigned char*)(ws + 10485888); // 131072 u8 (raw)
    unsigned char* lab0   = (unsigned char*)(ws + 10616960); // 131072 u8 (mapped)
    float* table  = (float*)(ws + 10748032);                 // 20*19 f32
    float* out    = (float*)d_out;

    // zero only counts (partials are fully overwritten each launch)
    hipMemsetAsync(counts, 0, 128, stream);

    k_labels<<<NPIX / 256,  256, 0, stream>>>(target, labels, lab0, counts);
    k_stats <<<NBLK,        256, 0, stream>>>(features, lab0, gpart);
    k_table <<<CP1,         256, 0, stream>>>(counts, gpart, fcw, Ave, CoV, Amount, ratio, table);
    k_apply <<<NB * CB * 4, 256, 0, stream>>>(y, labels, table, out);
}

// Round 8
// 242.280 us; speedup vs baseline: 1.1067x; 1.0889x over previous
//
#include <hip/hip_runtime.h>
#include <stdint.h>

// Problem constants (from reference)
#define NB   8
#define AB   256
#define HB   128
#define WB   128
#define CB   19
#define CP1  20
#define PLANE (HB*WB)          // 16384
#define NPIX  (NB*PLANE)       // 131072
#define NREP 8                 // replicated global accumulators (atomic contention /8)

typedef __attribute__((ext_vector_type(8))) short bf8_t;
typedef __attribute__((ext_vector_type(4))) float f4_t;
union ABu { bf8_t v; unsigned short u[8]; };

__device__ inline unsigned short f2bf(float f) {      // RNE fp32->bf16 (finite inputs)
    unsigned int u = __float_as_uint(f);
    return (unsigned short)((u + 0x7FFFu + ((u >> 16) & 1u)) >> 16);
}

// ---------------------------------------------------------------------------
// Kernel A: nearest-neighbor label downsample -> raw u8 + mapped u8, + counts
// ---------------------------------------------------------------------------
__global__ __launch_bounds__(256) void k_labels(const int* __restrict__ target,
                                                unsigned char* __restrict__ labels,
                                                unsigned char* __restrict__ lab0,
                                                float* __restrict__ counts) {
    __shared__ int hist[CP1];
    int tid = threadIdx.x;
    if (tid < CP1) hist[tid] = 0;
    __syncthreads();

    int p = blockIdx.x * 256 + tid;          // p in [0, NPIX)
    int n   = p >> 14;
    int rem = p & 16383;
    int h   = rem >> 7;
    int w   = rem & 127;
    size_t idx = (size_t)n * 1048576 + (size_t)h * 8192 + (size_t)w * 8;
    int l = target[idx];
    labels[p] = (unsigned char)l;
    int m = (l == 255) ? 0 : ((l >= 0 && l < CP1) ? l : 0);
    lab0[p] = (unsigned char)m;
    atomicAdd(&hist[m], 1);
    __syncthreads();
    if (tid < CP1) atomicAdd(&counts[tid], (float)hist[tid]);
}

// ---------------------------------------------------------------------------
// Kernel B (v3 == round-3 winner): per-class sum/sumsq via MFMA.
// S[l,a] = onehot[l,p] . F[a,p]; one-hot built in-register from labels.
// Block = 4 waves; wave owns 16 channels, block owns 64 ch x 512 px.
// Grid = 8n x 32pc x 4cg = 1024. Atomic epilogue into NREP replicas
// (A/B-proven faster than per-block partial writes: r3 244 vs r7 264 µs).
// ---------------------------------------------------------------------------
__global__ __launch_bounds__(256) void k_stats(const float* __restrict__ features,
                                               const unsigned char* __restrict__ lab0,
                                               float* __restrict__ gsumR,
                                               float* __restrict__ gsqR) {
    __shared__ uint2 labs[64];               // 512 labels
    const int tid  = threadIdx.x;
    const int lane = tid & 63;
    const int w    = tid >> 6;

    const int bx = blockIdx.x;
    const int cg = bx & 3;                   // channel group (64 ch)
    const int pc = (bx >> 2) & 31;           // pixel chunk (512 px)
    const int n  = bx >> 7;
    const int rep = bx & (NREP - 1);

    if (tid < 64)
        labs[tid] = ((const uint2*)(lab0 + (size_t)n * PLANE + pc * 512))[tid];
    __syncthreads();

    const int col = lane & 15;               // channel-within-tile, == B col, == D col
    const int pg  = (lane >> 4) * 8;         // k sub-offset within 32-pixel step
    const int ch  = cg * 64 + w * 16 + col;
    const float* fbase = features + ((size_t)(n * AB + ch)) * PLANE + pc * 512 + pg;

    f4_t aS0 = {0.f,0.f,0.f,0.f}, aQ0 = {0.f,0.f,0.f,0.f};   // classes 0-15
    f4_t aS1 = {0.f,0.f,0.f,0.f}, aQ1 = {0.f,0.f,0.f,0.f};   // classes 16-19

    const unsigned int t0 = (unsigned int)col;
    const unsigned int t1 = 16u + (unsigned int)col;

    #pragma unroll 4
    for (int t = 0; t < 16; ++t) {
        float4 va = *(const float4*)(fbase + t * 32);
        float4 vb = *(const float4*)(fbase + t * 32 + 4);
        uint2 lw = labs[(t * 32 + pg) >> 3];
        unsigned int bb[8] = { lw.x & 255u, (lw.x >> 8) & 255u, (lw.x >> 16) & 255u, lw.x >> 24,
                               lw.y & 255u, (lw.y >> 8) & 255u, (lw.y >> 16) & 255u, lw.y >> 24 };
        float fv[8] = { va.x, va.y, va.z, va.w, vb.x, vb.y, vb.z, vb.w };
        ABu a0, a1, bs, bq;
        #pragma unroll
        for (int j = 0; j < 8; ++j) {
            a0.u[j] = (bb[j] == t0) ? (unsigned short)0x3F80 : (unsigned short)0;
            a1.u[j] = (bb[j] == t1) ? (unsigned short)0x3F80 : (unsigned short)0;
            bs.u[j] = f2bf(fv[j]);
            bq.u[j] = f2bf(fv[j] * fv[j]);
        }
        aS0 = __builtin_amdgcn_mfma_f32_16x16x32_bf16(a0.v, bs.v, aS0, 0, 0, 0);
        aS1 = __builtin_amdgcn_mfma_f32_16x16x32_bf16(a1.v, bs.v, aS1, 0, 0, 0);
        aQ0 = __builtin_amdgcn_mfma_f32_16x16x32_bf16(a0.v, bq.v, aQ0, 0, 0, 0);
        aQ1 = __builtin_amdgcn_mfma_f32_16x16x32_bf16(a1.v, bq.v, aQ1, 0, 0, 0);
    }

    // D layout (m89): col = lane&15 (channel), row = (lane>>4)*4 + reg (class)
    float* gs = gsumR + rep * (CP1 * 256);
    float* gq = gsqR  + rep * (CP1 * 256);
    const int rbase = (lane >> 4) * 4;
    #pragma unroll
    for (int r = 0; r < 4; ++r) {
        atomicAdd(&gs[(rbase + r) * 256 + ch], aS0[r]);
        atomicAdd(&gq[(rbase + r) * 256 + ch], aQ0[r]);
    }
    if (rbase == 0) {                        // rows 0-3 of tile2 = classes 16-19
        #pragma unroll
        for (int r = 0; r < 4; ++r) {
            atomicAdd(&gs[(16 + r) * 256 + ch], aS1[r]);
            atomicAdd(&gq[(16 + r) * 256 + ch], aQ1[r]);
        }
    }
}

// ---------------------------------------------------------------------------
// Kernel C: reduce replicas, ave/var/new_cov -> sigma2 table [CP1][CB]
// ---------------------------------------------------------------------------
__global__ __launch_bounds__(256) void k_table(const float* __restrict__ counts,
                                               const float* __restrict__ gsumR,
                                               const float* __restrict__ gsqR,
                                               const float* __restrict__ fcw,
                                               const float* __restrict__ Ave,
                                               const float* __restrict__ CoV,
                                               const float* __restrict__ Amount,
                                               const int* __restrict__ ratio_p,
                                               float* __restrict__ table) {
    __shared__ float ncov_s[256];
    __shared__ float wl_s[256];
    int t = threadIdx.x;
    int l = blockIdx.x;

    float sum = 0.f, sq = 0.f;
    #pragma unroll
    for (int r = 0; r < NREP; ++r) {
        sum += gsumR[r * (CP1 * 256) + l * 256 + t];
        sq  += gsqR [r * (CP1 * 256) + l * 256 + t];
    }

    float cnt  = counts[l];
    float cntc = (cnt == 0.f) ? 1.f : cnt;
    float ave  = sum / cntc;
    float var  = sq / cntc - ave * ave;
    float denom = cnt + Amount[l];
    float wcv  = (denom > 0.f) ? cnt / denom : 0.f;
    float d0   = Ave[l * 256 + t] - ave;
    float ncov = CoV[l * 256 + t] * (1.f - wcv) + var * wcv + wcv * (1.f - wcv) * d0 * d0;

    ncov_s[t] = ncov;
    int lwr = (l < CB) ? l : (CB - 1);       // row 19 never used (counts[19]==0)
    wl_s[t] = fcw[lwr * 256 + t];
    __syncthreads();

    int wv = t >> 6, lane = t & 63;
    float ratio_f = (float)(*ratio_p);
    for (int c = wv; c < CB; c += 4) {
        float4 nc = *(const float4*)&ncov_s[lane * 4];
        float4 wl = *(const float4*)&wl_s[lane * 4];
        float4 wc = *(const float4*)&fcw[c * 256 + lane * 4];
        float e0 = wc.x - wl.x, e1 = wc.y - wl.y, e2 = wc.z - wl.z, e3 = wc.w - wl.w;
        float r = nc.x * e0 * e0 + nc.y * e1 * e1 + nc.z * e2 * e2 + nc.w * e3 * e3;
        #pragma unroll
        for (int off = 32; off; off >>= 1) r += __shfl_down(r, off);
        if (lane == 0) table[l * CB + c] = ratio_f * r;
    }
}

// ---------------------------------------------------------------------------
// Kernel D: out[n,c,h,w] = y[n,c,h,w] + 0.5 * table[lab[n,h,w]][c] * keep
// ---------------------------------------------------------------------------
__global__ __launch_bounds__(256) void k_apply(const float* __restrict__ y,
                                               const unsigned char* __restrict__ labels,
                                               const float* __restrict__ table,
                                               float* __restrict__ out) {
    __shared__ float tab[CP1 * CB];
    int tid = threadIdx.x;
    for (int i = tid; i < CP1 * CB; i += 256) tab[i] = table[i];
    __syncthreads();

    int b = blockIdx.x;
    int chunk = b & 3;
    int c = (b >> 2) % CB;
    int n = b / (4 * CB);

    const float* ybase = y + ((size_t)(n * CB + c)) * PLANE;
    float* obase = out + ((size_t)(n * CB + c)) * PLANE;
    const unsigned char* lbase = labels + (size_t)n * PLANE;

    #pragma unroll
    for (int it = 0; it < 4; ++it) {
        int pix = chunk * 4096 + it * 1024 + tid * 4;
        float4 yv = *reinterpret_cast<const float4*>(ybase + pix);
        unsigned int lwv = *reinterpret_cast<const unsigned int*>(lbase + pix);
        float ya[4] = {yv.x, yv.y, yv.z, yv.w};
        float o[4];
        #pragma unroll
        for (int j = 0; j < 4; ++j) {
            int l = (lwv >> (8 * j)) & 255;
            bool keep = (l != 255);
            int lab0i = keep ? (l < CP1 ? l : 0) : 0;
            float s = tab[lab0i * CB + c];
            o[j] = ya[j] + (keep ? 0.5f * s : 0.f);
        }
        *reinterpret_cast<float4*>(obase + pix) = make_float4(o[0], o[1], o[2], o[3]);
    }
}

// ---------------------------------------------------------------------------
extern "C" void kernel_launch(void* const* d_in, const int* in_sizes, int n_in,
                              void* d_out, int out_size, void* d_ws, size_t ws_size,
                              hipStream_t stream) {
    const float* features = (const float*)d_in[0];   // [8,256,128,128]
    const float* y        = (const float*)d_in[1];   // [8,19,128,128]
    const float* fcw      = (const float*)d_in[2];   // [19,256]
    const float* Ave      = (const float*)d_in[3];   // [20,256]
    const float* CoV      = (const float*)d_in[4];   // [20,256]
    const float* Amount   = (const float*)d_in[5];   // [20]
    const int*   target   = (const int*)d_in[6];     // [8,1024,1024]
    const int*   ratio    = (const int*)d_in[7];     // scalar

    char* ws = (char*)d_ws;
    float* counts = (float*)(ws + 0);                       // 20 f32 (pad 128 B)
    float* gsumR  = (float*)(ws + 128);                     // 8*20*256 f32 = 163840 B
    float* gsqR   = (float*)(ws + 128 + 163840);            // 8*20*256 f32
    unsigned char* labels = (unsigned char*)(ws + 327808);  // 131072 u8 (raw)
    unsigned char* lab0   = (unsigned char*)(ws + 458880);  // 131072 u8 (mapped)
    float* table  = (float*)(ws + 589952);                  // 20*19 f32
    float* out    = (float*)d_out;

    // zero counts + replicated accumulators
    hipMemsetAsync(ws, 0, 327808, stream);

    k_labels<<<NPIX / 256,   256, 0, stream>>>(target, labels, lab0, counts);
    k_stats <<<NB * 32 * 4,  256, 0, stream>>>(features, lab0, gsumR, gsqR);
    k_table <<<CP1,          256, 0, stream>>>(counts, gsumR, gsqR, fcw, Ave, CoV, Amount, ratio, table);
    k_apply <<<NB * CB * 4,  256, 0, stream>>>(y, labels, table, out);
}